// Round 9
// baseline (476.111 us; speedup 1.0000x reference)
//
#include <hip/hip_runtime.h>
#include <stdint.h>

// HeatDiffusion: out = rownorm( mask_topk16_sym(expm(-5*adj)) symmetrized + I )
// N=4096. s=1, single deg-4 Taylor (identity-offset):
//   Ms = -5*adj/2, M2 = Ms^2, G = Ms/6 + M2/24
//   Y  = Ms + M2/2 + M2*G        (heat = I + Y = T4(Ms))
// R11: k_topk register radix-select; k_final vectorized. (439us)
// R12: 256^2 tile FAILED via launch_bounds(512,2) VGPR cap 128 -> acc spill.
// R13: counted-sync K-loop — neutral. R14/R16: epilogue frag transpose
// (uint2/u32 packed epilogue IO) — WIN, 390.7us, gemm 117.7us each.
// R17/R18: 256x256 tile, BK=128, 8 waves (2M x 4N), 512 thr,
// __launch_bounds__(512,1) so the 128-VGPR accumulator fits the 256-reg
// tier (R12's spill fix). K-loop is the PROVEN R13 pattern: one vmcnt(0)+
// s_barrier per K-iter, stage next tile after barrier, setprio around MFMA.
// 128KB dbuf LDS, 1 block/CU, 256 blocks (no tail). Epilogue = R16 frag
// transpose; GEMM1 single-pass w/ full 256^2 fp8 stage tile; GEMM2 two
// M-half passes for the bf16 transpose tile. FLOP per staged LDS byte 2x.
// R18 fixes R17's Ct16 writeout (was 4 chunks/thread = half the columns;
// now 8 chunks/thread covering the full 256x128 half-tile).

#define NN 4096
#define TP 136    // u16 pitch (272B, 16B-aligned), bf16 transpose half-tile
#define TP8 272   // byte pitch, fp8 transpose tile

typedef unsigned short u16;
typedef unsigned char u8;
typedef __attribute__((ext_vector_type(8))) int v8i;
typedef __attribute__((ext_vector_type(4))) float f32x4;

__device__ __forceinline__ float bf2f(u16 u) {
  return __uint_as_float(((unsigned int)u) << 16);
}
__device__ __forceinline__ u16 f2bf(float f) {  // round-to-nearest-even
  unsigned int u = __float_as_uint(f);
  return (u16)((u + 0x7fffu + ((u >> 16) & 1u)) >> 16);
}
__device__ __forceinline__ unsigned int pk2bf(float a, float b) {
  return (unsigned int)f2bf(a) | ((unsigned int)f2bf(b) << 16);
}
// float -> OCP e4m3fn, RNE. Caller guarantees |f| <= 440 and finite.
__device__ __forceinline__ u8 f2e4m3(float f) {
  unsigned int u = __float_as_uint(f);
  unsigned int sign = (u >> 24) & 0x80u;
  int e8 = (int)((u >> 23) & 0xFF) - 127 + 7;
  if (e8 >= 1) {
    unsigned int man = u & 0x7FFFFFu;
    unsigned int m = man >> 20;
    unsigned int rem = man & 0xFFFFFu;
    if (rem > 0x80000u || (rem == 0x80000u && (m & 1u))) ++m;
    if (m == 8u) { m = 0u; ++e8; }
    return (u8)(sign | ((unsigned)e8 << 3) | m);
  } else {
    float af = __uint_as_float(u & 0x7FFFFFFFu);
    int q = (int)rintf(af * 512.0f);          // subnormal quantum 2^-9
    if (q >= 8) return (u8)(sign | (1u << 3)); // rounds up to min normal
    return (u8)(sign | (unsigned)q);
  }
}

// async global->LDS, 16B/lane (global_load_lds_dwordx4); LDS dest must be
// wave-uniform base + lane*16 — chunk mapping guarantees that.
__device__ __forceinline__ void async16(const void* g, void* l) {
  auto gp = reinterpret_cast<const __attribute__((address_space(1))) unsigned int*>(
      reinterpret_cast<uintptr_t>(g));
  auto lp = reinterpret_cast<__attribute__((address_space(3))) unsigned int*>(
      reinterpret_cast<uintptr_t>(l));
  __builtin_amdgcn_global_load_lds(gp, lp, 16, 0, 0);
}

// ---- adj -> Ms bf16, Ms fp8 (x2^19), Ms^T fp8 (x2^19), fused -------------
extern "C" __global__ void __launch_bounds__(256) k_split_tr(
    const float* __restrict__ src, u16* __restrict__ Z16,
    u8* __restrict__ Z8, u8* __restrict__ Zt8, float s, float s8) {
  __shared__ float tile[64][65];
  const int tx = threadIdx.x & 63;
  const int ty = threadIdx.x >> 6;
  const int r0 = blockIdx.y * 64, c0 = blockIdx.x * 64;
  for (int r = ty; r < 64; r += 4) {
    size_t g = (size_t)(r0 + r) * NN + (c0 + tx);
    float v = s * src[g];
    tile[r][tx] = v;
    Z16[g] = f2bf(v);
    Z8[g] = f2e4m3(v * s8);
  }
  __syncthreads();
  for (int r = ty; r < 64; r += 4)
    Zt8[(size_t)(c0 + r) * NN + (r0 + tx)] = f2e4m3(tile[tx][r] * s8);
}

// ---- FP8 GEMM, 256^2 tile, counted-sync: vc = accScale*(A8*Bt8^T)+... ----
// writes C16 = bf16(vc); if C8: C8 = fp8(vc*sC8), C8t = fp8(t*sT8)^T;
// if Ct16 (last): Ct16 = bf16(t)^T, where t = tv*acc*accScale + tx*X + ty*Y.
// 8 waves (2M x 4N), per-wave 128x64 = 8x4 frags of 16x16x128 f8f6f4.
extern "C" __global__ void __launch_bounds__(512, 1) k_gemm8(
    const u8* __restrict__ A8, const u8* __restrict__ Bt8,
    u16* __restrict__ C16, u8* __restrict__ C8, u8* __restrict__ C8t,
    u16* __restrict__ Ct16,
    const u16* __restrict__ X16, const u16* __restrict__ Y16,
    float accScale, float e1, float e2,
    float tv, float tx, float ty, float sC8, float sT8) {
  // 2 bufs x (A 32KB | B 32KB) = 128KB; epilogue overlays buf space:
  //   frag scratch 0..20KB (8 waves x 2560B), t-tile at 24576 (<= 70KB)
  __shared__ alignas(16) u8 smem8[131072];

  const int tid  = threadIdx.x;
  const int lane = tid & 63;
  const int wave = tid >> 6;
  const int wr = wave >> 2;          // 0..1  M-half
  const int wc = wave & 3;           // 0..3  N-quarter
  const int quad = lane >> 4;
  const int lrow = lane & 15;

  // XCD map: 16x16 tile grid, each XCD gets a 4M x 8N band
  const int bid = blockIdx.x;
  const int xcd = bid & 7, ii = bid >> 3;
  const int m0 = ((xcd & 3) * 4 + (ii & 3)) * 256;
  const int n0 = ((xcd >> 2) * 8 + (ii >> 2)) * 256;

  f32x4 acc[8][4];
#pragma unroll
  for (int i = 0; i < 8; ++i)
#pragma unroll
    for (int j = 0; j < 4; ++j) acc[i][j] = (f32x4){0.f, 0.f, 0.f, 0.f};

  // staging: plane tile 256x128B = 32KB = 2048 chunks of 16B; 4/thread.
  // XOR swizzle within each 128B row: chunk q -> (row=q>>3, col16=((q&7)^(row&7))*16)
  unsigned int ga[4], gb[4];
  int lo[4];
#pragma unroll
  for (int c = 0; c < 4; ++c) {
    int q = tid + c * 512;                // 0..2047
    int row = q >> 3;                     // 0..255
    int col = ((q & 7) ^ (row & 7)) * 16;
    ga[c] = (unsigned int)(m0 + row) * NN + col;
    gb[c] = (unsigned int)(n0 + row) * NN + col;
    lo[c] = q * 16;
  }

  // fragment chunk column (post-swizzle); frag rows r have r&7 == lrow&7
  const int c0f = (quad * 2) ^ (lrow & 7);

  // prologue: tile 0 -> buf 0
#pragma unroll
  for (int c = 0; c < 4; ++c) {
    async16(A8 + ga[c], smem8 + lo[c]);
    async16(Bt8 + gb[c], smem8 + 32768 + lo[c]);
  }

#pragma unroll 2
  for (int it = 0; it < 32; ++it) {
    const u8* sA = smem8 + (it & 1) * 65536;
    const u8* sB = sA + 32768;
    u8* nb = smem8 + (((it & 1) ^ 1) * 65536);

    // counted loads (tile it) were issued one full iteration ago -> ~free
    asm volatile("s_waitcnt vmcnt(0)" ::: "memory");
    __builtin_amdgcn_s_barrier();
    asm volatile("" ::: "memory");

    if (it < 31) {
      const int k = (it + 1) << 7;
#pragma unroll
      for (int c = 0; c < 4; ++c) {
        async16(A8 + ga[c] + k, nb + lo[c]);
        async16(Bt8 + gb[c] + k, nb + 32768 + lo[c]);
      }
      asm volatile("" ::: "memory");   // keep load-issue ahead of compute
    }

    v8i bv[4];
#pragma unroll
    for (int ni = 0; ni < 4; ++ni) {
      const int r = wc * 64 + ni * 16 + lrow;
      const uint4 q0 = *(const uint4*)&sB[r * 128 + c0f * 16];
      const uint4 q1 = *(const uint4*)&sB[r * 128 + (c0f ^ 1) * 16];
      bv[ni] = (v8i){(int)q0.x, (int)q0.y, (int)q0.z, (int)q0.w,
                     (int)q1.x, (int)q1.y, (int)q1.z, (int)q1.w};
    }
    __builtin_amdgcn_s_setprio(1);
#pragma unroll
    for (int mi = 0; mi < 8; ++mi) {
      const int r = wr * 128 + mi * 16 + lrow;
      const uint4 q0 = *(const uint4*)&sA[r * 128 + c0f * 16];
      const uint4 q1 = *(const uint4*)&sA[r * 128 + (c0f ^ 1) * 16];
      const v8i av = (v8i){(int)q0.x, (int)q0.y, (int)q0.z, (int)q0.w,
                           (int)q1.x, (int)q1.y, (int)q1.z, (int)q1.w};
#pragma unroll
      for (int ni = 0; ni < 4; ++ni)
        acc[mi][ni] = __builtin_amdgcn_mfma_scale_f32_16x16x128_f8f6f4(
            av, bv[ni], acc[mi][ni], 0, 0, 0, 0x7F, 0, 0x7F);
    }
    __builtin_amdgcn_s_setprio(0);
    // no end barrier: next iteration's vmcnt+barrier provides the sync
  }
  __syncthreads();   // guard epilogue LDS overlay vs slowest wave's reads

  const bool hasX = (X16 != nullptr);
  const bool hasY = (Y16 != nullptr);
  const bool last = (Ct16 != nullptr);

  // Per-wave f32 transpose scratch: 2 slots x 16 rows x pitch20 f32.
  float* scr0 = (float*)(smem8 + wave * 2560);
  float* scr1 = scr0 + 320;
  u16* t16 = (u16*)(smem8 + 24576);      // last: 256 x TP u16 (half-tile)
  u8*  t8  = smem8 + 24576;              // else: 256 x TP8 bytes (full tile)

#pragma unroll 1
  for (int h = 0; h < (last ? 2 : 1); ++h) {
    if (!last || wr == h) {
#pragma unroll
      for (int f = 0; f < 32; ++f) {
        const int mi = f >> 2, ni = f & 3;
        float* S = (f & 1) ? scr1 : scr0;
        // write own sub-rows, read back transposed (4 consecutive cols)
#pragma unroll
        for (int r = 0; r < 4; ++r)
          S[(quad * 4 + r) * 20 + lrow] = acc[mi][ni][r];
        asm volatile("" ::: "memory");   // order scratch writes before read
        const f32x4 tt = *(const f32x4*)&S[lrow * 20 + quad * 4];

        const int lml = wr * 128 + mi * 16 + lrow;       // local row
        const int lnc = wc * 64 + ni * 16 + quad * 4;    // first of 4 cols
        const size_t g = (size_t)(m0 + lml) * NN + (n0 + lnc);

        float xv[4] = {0.f, 0.f, 0.f, 0.f}, yv[4] = {0.f, 0.f, 0.f, 0.f};
        if (hasX) {
          const uint2 xw = *(const uint2*)&X16[g];
          xv[0] = bf2f((u16)(xw.x & 0xFFFFu)); xv[1] = bf2f((u16)(xw.x >> 16));
          xv[2] = bf2f((u16)(xw.y & 0xFFFFu)); xv[3] = bf2f((u16)(xw.y >> 16));
        }
        if (hasY) {
          const uint2 yw = *(const uint2*)&Y16[g];
          yv[0] = bf2f((u16)(yw.x & 0xFFFFu)); yv[1] = bf2f((u16)(yw.x >> 16));
          yv[2] = bf2f((u16)(yw.y & 0xFFFFu)); yv[3] = bf2f((u16)(yw.y >> 16));
        }
        float vc[4], t[4];
#pragma unroll
        for (int r = 0; r < 4; ++r) {
          const float vraw = tt[r] * accScale;
          vc[r] = vraw + e1 * xv[r] + e2 * yv[r];
          t[r] = tv * vraw + tx * xv[r] + ty * yv[r];
        }
        uint2 cw;
        cw.x = pk2bf(vc[0], vc[1]);
        cw.y = pk2bf(vc[2], vc[3]);
        *(uint2*)&C16[g] = cw;               // read-before-write vs X16 alias
        if (last) {
          const int lmh = mi * 16 + lrow;    // col within this M-half
#pragma unroll
          for (int r = 0; r < 4; ++r) t16[(lnc + r) * TP + lmh] = f2bf(t[r]);
        } else {
          unsigned int c8w = (unsigned int)f2e4m3(vc[0] * sC8) |
                             ((unsigned int)f2e4m3(vc[1] * sC8) << 8) |
                             ((unsigned int)f2e4m3(vc[2] * sC8) << 16) |
                             ((unsigned int)f2e4m3(vc[3] * sC8) << 24);
          *(unsigned int*)&C8[g] = c8w;
#pragma unroll
          for (int r = 0; r < 4; ++r)
            t8[(lnc + r) * TP8 + lml] = f2e4m3(t[r] * sT8);
        }
      }
    }
    __syncthreads();                       // t tile ready
    if (last) {
      // coalesced bf16 Ct half: 256 rows x 128 cols = 4096 chunks of 16B
#pragma unroll
      for (int c = 0; c < 8; ++c) {
        const int q = tid + c * 512;
        const int row = q >> 4, p = q & 15;
        const uint4 v = *(const uint4*)&t16[row * TP + p * 8];
        *(uint4*)(Ct16 + (size_t)(n0 + row) * NN + m0 + h * 128 + p * 8) = v;
      }
      if (h == 0) __syncthreads();         // before pass-1 tile overwrite
    } else {
      // coalesced fp8 C8t: 256 rows x 256 cols = 4096 chunks of 16B
#pragma unroll
      for (int c = 0; c < 8; ++c) {
        const int q = tid + c * 512;
        const int row = q >> 4, p = q & 15;
        const uint4 v = *(const uint4*)&t8[row * TP8 + p * 16];
        *(uint4*)&C8t[(size_t)(n0 + row) * NN + m0 + p * 16] = v;
      }
    }
  }
}

// ---- per-row 16th-largest of heat = (Y + I): binary radix-select ---------
// Orderable key: u = (bits & sign) ? ~bits : bits|0x80000000 (monotone).
// All candidates are bf16-derived (fp32 low 16 bits = 0) except the diag
// (+1.0), which is the row MAX and never the 16th -> select on key>>16 only.
// Each thread owns 16 CONTIGUOUS candidates (j0 = tid*16) in registers;
// 16 rounds MSB->LSB, one barrier per round (fresh counter slot each).
extern "C" __global__ void __launch_bounds__(256) k_topk(
    const u16* __restrict__ Hh, float* __restrict__ thr) {
  __shared__ unsigned int s_cnt[16];
  const int row = blockIdx.x;
  const int tid = threadIdx.x;
  if (tid < 16) s_cnt[tid] = 0;

  const int j0 = tid * 16;
  const uint4* p = (const uint4*)(Hh + (size_t)row * NN + j0);
  const uint4 q0 = p[0], q1 = p[1];
  const unsigned int w[8] = {q0.x, q0.y, q0.z, q0.w, q1.x, q1.y, q1.z, q1.w};
  unsigned int k16[16];
#pragma unroll
  for (int i = 0; i < 16; ++i) {
    const unsigned int u = (i & 1) ? (w[i >> 1] >> 16) : (w[i >> 1] & 0xFFFFu);
    float v = bf2f((u16)u) + ((j0 + i == row) ? 1.f : 0.f);
    const unsigned int b = __float_as_uint(v);
    const unsigned int key = (b & 0x80000000u) ? ~b : (b | 0x80000000u);
    k16[i] = (key >> 16) & 0xFFFFu;
  }
  __syncthreads();                     // covers s_cnt init (keys are private)

  unsigned int pref = 0, kk = 16;
#pragma unroll
  for (int b = 15; b >= 0; --b) {
    const unsigned int hiMask = (0xFFFFu << (b + 1)) & 0xFFFFu;
    const unsigned int want = pref & hiMask;
    unsigned int c = 0;
#pragma unroll
    for (int i = 0; i < 16; ++i)
      c += (((k16[i] & hiMask) == want) & ((k16[i] >> b) & 1u));
#pragma unroll
    for (int off = 32; off > 0; off >>= 1) c += __shfl_down(c, off);
    if ((tid & 63) == 0) atomicAdd(&s_cnt[15 - b], c);
    __syncthreads();                   // one barrier/round (fresh slot each)
    const unsigned int c1 = s_cnt[15 - b];
    if (c1 >= kk) pref |= (1u << b);
    else kk -= c1;
  }
  if (tid == 0) {
    const unsigned int key = pref << 16;
    const unsigned int bits = (key & 0x80000000u) ? (key & 0x7FFFFFFFu) : ~key;
    thr[row] = __uint_as_float(bits);
  }
}

// ---- mask + symmetrize + add I + row-normalize (heat = Y + I) ------------
// Fully vectorized — 16 contiguous elems/thread via uint4/float4, values
// kept in registers (no LDS round-trip).
extern "C" __global__ void __launch_bounds__(256) k_final(
    const u16* __restrict__ Hh,    // Y rows
    const u16* __restrict__ Th,    // Y^T rows
    const float* __restrict__ thr, float* __restrict__ out) {
  __shared__ float wsum[4];
  const int row = blockIdx.x;
  const int tid = threadIdx.x;
  const float ti = thr[row];
  const int j0 = tid * 16;

  const uint4* ph = (const uint4*)(Hh + (size_t)row * NN + j0);
  const uint4* pt = (const uint4*)(Th + (size_t)row * NN + j0);
  const uint4 h0 = ph[0], h1 = ph[1];
  const uint4 t0 = pt[0], t1 = pt[1];
  const unsigned int wh[8] = {h0.x, h0.y, h0.z, h0.w, h1.x, h1.y, h1.z, h1.w};
  const unsigned int wt[8] = {t0.x, t0.y, t0.z, t0.w, t1.x, t1.y, t1.z, t1.w};
  const float4* pr = (const float4*)(thr + j0);
  const float4 r0 = pr[0], r1 = pr[1], r2 = pr[2], r3 = pr[3];
  const float tj[16] = {r0.x, r0.y, r0.z, r0.w, r1.x, r1.y, r1.z, r1.w,
                        r2.x, r2.y, r2.z, r2.w, r3.x, r3.y, r3.z, r3.w};

  float vals[16];
  float s = 0.f;
#pragma unroll
  for (int i = 0; i < 16; ++i) {
    const float ind = (j0 + i == row) ? 1.f : 0.f;
    const unsigned int uh = (i & 1) ? (wh[i >> 1] >> 16) : (wh[i >> 1] & 0xFFFFu);
    const unsigned int ut = (i & 1) ? (wt[i >> 1] >> 16) : (wt[i >> 1] & 0xFFFFu);
    const float hij = bf2f((u16)uh) + ind;
    const float hji = bf2f((u16)ut) + ind;
    float val = (hij >= ti || hji >= tj[i]) ? 0.5f * (hij + hji) : 0.f;
    val += ind;                                   // + eye after masking
    vals[i] = val;
    s += val;
  }
#pragma unroll
  for (int off = 32; off > 0; off >>= 1) s += __shfl_down(s, off);
  if ((tid & 63) == 0) wsum[tid >> 6] = s;
  __syncthreads();
  const float inv = 1.f / (wsum[0] + wsum[1] + wsum[2] + wsum[3]);

  float* op = out + (size_t)row * NN + j0;
#pragma unroll
  for (int q = 0; q < 4; ++q) {
    float4 o;
    o.x = vals[q * 4 + 0] * inv;
    o.y = vals[q * 4 + 1] * inv;
    o.z = vals[q * 4 + 2] * inv;
    o.w = vals[q * 4 + 3] * inv;
    *(float4*)(op + q * 4) = o;
  }
}

extern "C" void kernel_launch(void* const* d_in, const int* in_sizes, int n_in,
                              void* d_out, int out_size, void* d_ws, size_t ws_size,
                              hipStream_t stream) {
  const float* adj = (const float*)d_in[0];
  char* ws = (char*)d_ws;
  const size_t U = (size_t)NN * NN;             // 16 MiB unit (fp8 plane size)
  // ws layout (8U + 16KB): u0-1 Ms16 (later overwritten in-place by Y bf16),
  // u2 MsF, u3 MstF, u4 M2F, u5 GtF, u6-7 Yt16, thr at 8U.
  u16* Ms16 = (u16*)(ws);                       // u0-1 (bf16); Y aliases this
  u8*  MsF  = (u8*)(ws + 2 * U);                // u2
  u8*  MstF = (u8*)(ws + 3 * U);                // u3
  u8*  M2F  = (u8*)(ws + 4 * U);                // u4
  u8*  GtF  = (u8*)(ws + 5 * U);                // u5
  u16* Yt16 = (u16*)(ws + 6 * U);               // u6-7 (Y^T bf16)
  float* thr = (float*)(ws + 8 * U);
  u16* Y16  = Ms16;                             // GEMM2 C16: same-elem RAW-safe
  u16* M2_16 = (u16*)d_out;                     // d_out lower 2U, scratch
  float* out = (float*)d_out;

  const dim3 b(256);
  const u16* n16 = nullptr;
  u8* n8 = nullptr;

  // 1) Ms = -5/2*adj: bf16 -> Ms16, fp8*2^19 -> MsF, (Ms^T)*2^19 -> MstF
  //    (|Ms|max = 2.5/4096 = 6.1e-4 -> *2^19 = 320 < 448 e4m3 max)
  k_split_tr<<<dim3(64, 64), b, 0, stream>>>(adj, Ms16, MsF, MstF,
                                             -2.5f, 0x1p19f);
  // 2) GEMM1: M2 = Ms*Ms; C=M2 (bf16 -> d_out, fp8*2^19 -> M2F);
  //    Ct = G^T = (Ms/6 + M2/24)^T fp8*2^21 -> GtF  (|G|max ~1.2e-4 -> 252)
  k_gemm8<<<dim3(256), dim3(512), 0, stream>>>(MsF, MstF, M2_16, M2F, GtF,
                                        (u16*)nullptr,
                                        Ms16, n16,
                                        0x1p-38f, 0.f, 0.f,
                                        1.f / 24.f, 1.f / 6.f, 0.f,
                                        0x1p19f, 0x1p21f);
  // 3) GEMM2: Y = M2*G + Ms + M2/2 -> Y16 (aliases Ms16; same-element
  //    read-before-write in epilogue, safe); Ct16 = Y^T -> Yt16. heat = I + Y.
  k_gemm8<<<dim3(256), dim3(512), 0, stream>>>(M2F, GtF, Y16, n8, n8, Yt16,
                                        Ms16, M2_16,
                                        0x1p-40f, 1.f, 0.5f,
                                        1.f, 1.f, 0.5f,
                                        1.f, 1.f);
  // 4) per-row 16th-largest of heat -> thr (radix-select, register-resident)
  k_topk<<<dim3(NN), b, 0, stream>>>(Y16, thr);
  // 5) mask/sym/normalize -> out (overwrites d_out; M2_16 dead)
  k_final<<<dim3(NN), b, 0, stream>>>(Y16, Yt16, thr, out);
}

// Round 12
// 385.033 us; speedup vs baseline: 1.2365x; 1.2365x over previous
//
#include <hip/hip_runtime.h>
#include <stdint.h>

// HeatDiffusion: out = rownorm( mask_topk16_sym(expm(-5*adj)) symmetrized + I )
// N=4096. s=1, single deg-4 Taylor (identity-offset):
//   Ms = -5*adj/2, M2 = Ms^2, G = Ms/6 + M2/24
//   Y  = Ms + M2/2 + M2*G        (heat = I + Y = T4(Ms))
// R11: k_topk register radix-select; k_final vectorized. (439us)
// R12/R18: 256^2 tile FAILED twice — hipcc caps 512-thr kernel at 128 arch
// VGPR (ignores launch_bounds min-waves) -> acc spill (WRITE 190-709MB).
// R13: counted-sync K-loop — neutral. R14/R16: epilogue frag transpose
// (uint2/u32 packed epilogue IO) — WIN, 390.7us, gemm 117.7us each.
// R19..R21 (unmeasured — infra failures): revert to R16 GEMM; vectorize
// k_split_tr IO (float4 loads, uint2 bf16 + packed-u32 fp8 stores, packed
// transposed stores) — kills the last scalar 2B/1B partial-line stores.
// GEMM untouched.

#define NN 4096
#define BM 128
#define BN 128
#define TP 140    // u16 pitch, bf16 epilogue-transpose tile (last GEMM)
#define TP8 144   // byte pitch, fp8 epilogue-transpose tile

typedef unsigned short u16;
typedef unsigned char u8;
typedef __attribute__((ext_vector_type(8))) int v8i;
typedef __attribute__((ext_vector_type(4))) float f32x4;

__device__ __forceinline__ float bf2f(u16 u) {
  return __uint_as_float(((unsigned int)u) << 16);
}
__device__ __forceinline__ u16 f2bf(float f) {  // round-to-nearest-even
  unsigned int u = __float_as_uint(f);
  return (u16)((u + 0x7fffu + ((u >> 16) & 1u)) >> 16);
}
__device__ __forceinline__ unsigned int pk2bf(float a, float b) {
  return (unsigned int)f2bf(a) | ((unsigned int)f2bf(b) << 16);
}
// float -> OCP e4m3fn, RNE. Caller guarantees |f| <= 440 and finite.
__device__ __forceinline__ u8 f2e4m3(float f) {
  unsigned int u = __float_as_uint(f);
  unsigned int sign = (u >> 24) & 0x80u;
  int e8 = (int)((u >> 23) & 0xFF) - 127 + 7;
  if (e8 >= 1) {
    unsigned int man = u & 0x7FFFFFu;
    unsigned int m = man >> 20;
    unsigned int rem = man & 0xFFFFFu;
    if (rem > 0x80000u || (rem == 0x80000u && (m & 1u))) ++m;
    if (m == 8u) { m = 0u; ++e8; }
    return (u8)(sign | ((unsigned)e8 << 3) | m);
  } else {
    float af = __uint_as_float(u & 0x7FFFFFFFu);
    int q = (int)rintf(af * 512.0f);          // subnormal quantum 2^-9
    if (q >= 8) return (u8)(sign | (1u << 3)); // rounds up to min normal
    return (u8)(sign | (unsigned)q);
  }
}
__device__ __forceinline__ unsigned int pk4e4m3(float a, float b, float c,
                                                float d) {
  return (unsigned int)f2e4m3(a) | ((unsigned int)f2e4m3(b) << 8) |
         ((unsigned int)f2e4m3(c) << 16) | ((unsigned int)f2e4m3(d) << 24);
}

// async global->LDS, 16B/lane (global_load_lds_dwordx4); LDS dest must be
// wave-uniform base + lane*16 — chunk mapping guarantees that.
__device__ __forceinline__ void async16(const void* g, void* l) {
  auto gp = reinterpret_cast<const __attribute__((address_space(1))) unsigned int*>(
      reinterpret_cast<uintptr_t>(g));
  auto lp = reinterpret_cast<__attribute__((address_space(3))) unsigned int*>(
      reinterpret_cast<uintptr_t>(l));
  __builtin_amdgcn_global_load_lds(gp, lp, 16, 0, 0);
}

// ---- adj -> Ms bf16, Ms fp8 (x2^19), Ms^T fp8 (x2^19), fused -------------
// Fully vectorized. Phase 1: float4 load, uint2 bf16 store, u32 fp8 store,
// LDS tile stash. Phase 2: 4 strided LDS reads -> packed u32 transposed
// store. LDS patterns are <=2-way bank-aliased (free).
extern "C" __global__ void __launch_bounds__(256) k_split_tr(
    const float* __restrict__ src, u16* __restrict__ Z16,
    u8* __restrict__ Z8, u8* __restrict__ Zt8, float s, float s8) {
  __shared__ float tile[64][65];
  const int tid = threadIdx.x;
  const int cx = (tid & 15) * 4;        // col 0,4,...,60
  const int ry = tid >> 4;              // 0..15
  const int r0 = blockIdx.y * 64, c0 = blockIdx.x * 64;
#pragma unroll
  for (int rr = 0; rr < 64; rr += 16) {
    const int r = rr + ry;
    const size_t g = (size_t)(r0 + r) * NN + (c0 + cx);
    const float4 a = *(const float4*)(src + g);
    const float v0 = s * a.x, v1 = s * a.y, v2 = s * a.z, v3 = s * a.w;
    tile[r][cx] = v0; tile[r][cx + 1] = v1;
    tile[r][cx + 2] = v2; tile[r][cx + 3] = v3;
    uint2 zw; zw.x = pk2bf(v0, v1); zw.y = pk2bf(v2, v3);
    *(uint2*)(Z16 + g) = zw;
    *(unsigned int*)(Z8 + g) = pk4e4m3(v0 * s8, v1 * s8, v2 * s8, v3 * s8);
  }
  __syncthreads();
  // Zt8[c][r] = fp8(tile[r][c]*s8): each thread packs 4 consecutive r into
  // one u32; wave writes 4 c-rows x 64B contiguous.
  const int rq = (tid & 15) * 4;        // r-block 0,4,...,60
  const int cy = tid >> 4;              // 0..15
#pragma unroll
  for (int cc = 0; cc < 64; cc += 16) {
    const int c = cc + cy;
    const unsigned int zt =
        pk4e4m3(tile[rq + 0][c] * s8, tile[rq + 1][c] * s8,
                tile[rq + 2][c] * s8, tile[rq + 3][c] * s8);
    *(unsigned int*)(Zt8 + (size_t)(c0 + c) * NN + r0 + rq) = zt;
  }
}

// ---- FP8 GEMM, counted-sync pipelined: vc = accScale*(A8*Bt8^T)+e1*X+e2*Y
// writes C16 = bf16(vc); if C8: C8 = fp8(vc*sC8), C8t = fp8(t*sT8)^T;
// if Ct16 (last): Ct16 = bf16(t)^T, where t = tv*acc*accScale + tx*X + ty*Y.
// 128x128 tile, BK=128, 4 waves x (4x4 of 16x16x128 f8f6f4, unit scales).
extern "C" __global__ void __launch_bounds__(256, 2) k_gemm8(
    const u8* __restrict__ A8, const u8* __restrict__ Bt8,
    u16* __restrict__ C16, u8* __restrict__ C8, u8* __restrict__ C8t,
    u16* __restrict__ Ct16,
    const u16* __restrict__ X16, const u16* __restrict__ Y16,
    float accScale, float e1, float e2,
    float tv, float tx, float ty, float sC8, float sT8) {
  // 2 buffers x (sA 16KB | sB 16KB) = 64KB; epilogue tiles overlay buf space
  __shared__ alignas(16) u8 smem8[65536];
  u16* smem16 = (u16*)smem8;

  const int tid  = threadIdx.x;
  const int lane = tid & 63;
  const int wave = tid >> 6;
  const int wr = wave >> 1, wc = wave & 1;
  const int quad = lane >> 4;
  const int lrow = lane & 15;

  // grouped swizzle: bands of 8x8 tiles for L2/L3 panel locality
  const int bid = blockIdx.x;
  const int group = bid >> 6, inb = bid & 63;
  const int m0 = ((group & 3) * 8 + (inb & 7)) * BM;
  const int n0 = ((group >> 2) * 8 + (inb >> 3)) * BN;

  f32x4 acc[4][4];
#pragma unroll
  for (int i = 0; i < 4; ++i)
#pragma unroll
    for (int j = 0; j < 4; ++j) acc[i][j] = (f32x4){0.f, 0.f, 0.f, 0.f};

  // staging: plane tile 128x128 fp8 = 16KB = 1024 chunks of 16B; 4/thread.
  // XOR swizzle: chunk q holds global (row=q>>3, col16=((q&7)^(row&7))*16).
  unsigned int ga[4], gb[4];
  int lo[4];
#pragma unroll
  for (int c = 0; c < 4; ++c) {
    int q = tid + c * 256;
    int row = q >> 3;
    int col = ((q & 7) ^ (row & 7)) * 16;
    ga[c] = (unsigned int)(m0 + row) * NN + col;
    gb[c] = (unsigned int)(n0 + row) * NN + col;
    lo[c] = q * 16;
  }

  // fragment chunk column (post-swizzle); rows r have r&7 == lrow&7
  const int c0f = (quad * 2) ^ (lrow & 7);   // lower 16B of the 32B k-group

  // prologue: tile 0 -> buf 0
#pragma unroll
  for (int c = 0; c < 4; ++c) {
    async16(A8 + ga[c], smem8 + lo[c]);
    async16(Bt8 + gb[c], smem8 + 16384 + lo[c]);
  }

#pragma unroll 2
  for (int it = 0; it < 32; ++it) {
    u8* sCur = smem8 + (it & 1) * 32768;
    u8* sNxt = smem8 + ((it & 1) ^ 1) * 32768;

    // all counted loads (tile it, issued one full iteration ago) -> ~free
    asm volatile("s_waitcnt vmcnt(0)" ::: "memory");
    __builtin_amdgcn_s_barrier();
    asm volatile("" ::: "memory");

    if (it < 31) {
      const int k = (it + 1) << 7;
#pragma unroll
      for (int c = 0; c < 4; ++c) {
        async16(A8 + ga[c] + k, sNxt + lo[c]);
        async16(Bt8 + gb[c] + k, sNxt + 16384 + lo[c]);
      }
      asm volatile("" ::: "memory");   // keep load-issue ahead of compute
    }

    const u8* sA = sCur;
    const u8* sB = sCur + 16384;
    v8i av[4], bv[4];
#pragma unroll
    for (int mi = 0; mi < 4; ++mi) {
      const int r = wr * 64 + mi * 16 + lrow;
      const uint4 q0 = *(const uint4*)&sA[r * 128 + c0f * 16];
      const uint4 q1 = *(const uint4*)&sA[r * 128 + (c0f ^ 1) * 16];
      av[mi] = (v8i){(int)q0.x, (int)q0.y, (int)q0.z, (int)q0.w,
                     (int)q1.x, (int)q1.y, (int)q1.z, (int)q1.w};
    }
#pragma unroll
    for (int ni = 0; ni < 4; ++ni) {
      const int r = wc * 64 + ni * 16 + lrow;
      const uint4 q0 = *(const uint4*)&sB[r * 128 + c0f * 16];
      const uint4 q1 = *(const uint4*)&sB[r * 128 + (c0f ^ 1) * 16];
      bv[ni] = (v8i){(int)q0.x, (int)q0.y, (int)q0.z, (int)q0.w,
                     (int)q1.x, (int)q1.y, (int)q1.z, (int)q1.w};
    }
    __builtin_amdgcn_s_setprio(1);
#pragma unroll
    for (int mi = 0; mi < 4; ++mi)
#pragma unroll
      for (int ni = 0; ni < 4; ++ni)
        acc[mi][ni] = __builtin_amdgcn_mfma_scale_f32_16x16x128_f8f6f4(
            av[mi], bv[ni], acc[mi][ni], 0, 0, 0, 0x7F, 0, 0x7F);
    __builtin_amdgcn_s_setprio(0);
    // no end barrier: next iteration's vmcnt+barrier provides the sync
  }
  __syncthreads();   // guard epilogue LDS overlay vs slowest wave's reads

  const bool hasX = (X16 != nullptr);
  const bool hasY = (Y16 != nullptr);
  const bool last = (Ct16 != nullptr);

  // Per-wave f32 transpose scratch: 2 slots x 16 rows x pitch20 f32 (1280B).
  // Region 36864..47104 sits above both staging tiles (t16 <= 35.8KB,
  // t8 <= 18.4KB). Wave-private -> no barrier needed for scratch (HW LDS is
  // in-order per wave; asm fence blocks compile-time reordering).
  float* scr0 = (float*)(smem8 + 36864 + wave * 2560);
  float* scr1 = scr0 + 320;

#pragma unroll
  for (int f = 0; f < 16; ++f) {
    const int mi = f >> 2, ni = f & 3;
    float* S = (f & 1) ? scr1 : scr0;
    // write own sub-rows, read back transposed (4 consecutive cols of 1 row)
#pragma unroll
    for (int r = 0; r < 4; ++r) S[(quad * 4 + r) * 20 + lrow] = acc[mi][ni][r];
    asm volatile("" ::: "memory");     // order scratch writes before read
    const f32x4 tt = *(const f32x4*)&S[lrow * 20 + quad * 4];

    const int lml = wr * 64 + mi * 16 + lrow;        // local row
    const int lnc = wc * 64 + ni * 16 + quad * 4;    // first of 4 local cols
    const int gm = m0 + lml;
    const size_t g = (size_t)gm * NN + (n0 + lnc);

    float xv[4] = {0.f, 0.f, 0.f, 0.f}, yv[4] = {0.f, 0.f, 0.f, 0.f};
    if (hasX) {
      const uint2 xw = *(const uint2*)&X16[g];
      xv[0] = bf2f((u16)(xw.x & 0xFFFFu)); xv[1] = bf2f((u16)(xw.x >> 16));
      xv[2] = bf2f((u16)(xw.y & 0xFFFFu)); xv[3] = bf2f((u16)(xw.y >> 16));
    }
    if (hasY) {
      const uint2 yw = *(const uint2*)&Y16[g];
      yv[0] = bf2f((u16)(yw.x & 0xFFFFu)); yv[1] = bf2f((u16)(yw.x >> 16));
      yv[2] = bf2f((u16)(yw.y & 0xFFFFu)); yv[3] = bf2f((u16)(yw.y >> 16));
    }
    float vc[4], t[4];
#pragma unroll
    for (int r = 0; r < 4; ++r) {
      const float vraw = tt[r] * accScale;
      vc[r] = vraw + e1 * xv[r] + e2 * yv[r];
      t[r] = tv * vraw + tx * xv[r] + ty * yv[r];
    }
    uint2 cw;
    cw.x = pk2bf(vc[0], vc[1]);
    cw.y = pk2bf(vc[2], vc[3]);
    *(uint2*)&C16[g] = cw;                   // read-before-write vs X16 alias
    if (last) {
#pragma unroll
      for (int r = 0; r < 4; ++r) smem16[(lnc + r) * TP + lml] = f2bf(t[r]);
    } else {
      *(unsigned int*)&C8[g] = pk4e4m3(vc[0] * sC8, vc[1] * sC8,
                                       vc[2] * sC8, vc[3] * sC8);
#pragma unroll
      for (int r = 0; r < 4; ++r)
        smem8[(lnc + r) * TP8 + lml] = f2e4m3(t[r] * sT8);
    }
  }
  __syncthreads();

  if (last) {
    // coalesced bf16 Ct: wave covers local-n rows [wave*32, wave*32+32)
    const int sr = lane >> 4;
    const int c16 = lane & 15;
#pragma unroll
    for (int it = 0; it < 8; ++it) {
      const int row = wave * 32 + it * 4 + sr;
      const u16* srcp = &smem16[row * TP + c16 * 8];
      uint2 lo8 = *(const uint2*)(srcp);
      uint2 hi8 = *(const uint2*)(srcp + 4);
      uint4 q; q.x = lo8.x; q.y = lo8.y; q.z = hi8.x; q.w = hi8.y;
      *(uint4*)(Ct16 + (size_t)(n0 + row) * NN + m0 + c16 * 8) = q;
    }
  } else {
    // coalesced fp8 C8t: 1024 chunks of 16B, 4/thread
#pragma unroll
    for (int cc = 0; cc < 4; ++cc) {
      const int qq = tid + cc * 256;
      const int row = qq >> 3, p = qq & 7;
      uint4 v = *(const uint4*)&smem8[row * TP8 + p * 16];
      *(uint4*)&C8t[(size_t)(n0 + row) * NN + m0 + p * 16] = v;
    }
  }
}

// ---- per-row 16th-largest of heat = (Y + I): binary radix-select ---------
// Orderable key: u = (bits & sign) ? ~bits : bits|0x80000000 (monotone).
// All candidates are bf16-derived (fp32 low 16 bits = 0) except the diag
// (+1.0), which is the row MAX and never the 16th -> select on key>>16 only.
// Each thread owns 16 CONTIGUOUS candidates (j0 = tid*16) in registers;
// 16 rounds MSB->LSB, one barrier per round (fresh counter slot each).
extern "C" __global__ void __launch_bounds__(256) k_topk(
    const u16* __restrict__ Hh, float* __restrict__ thr) {
  __shared__ unsigned int s_cnt[16];
  const int row = blockIdx.x;
  const int tid = threadIdx.x;
  if (tid < 16) s_cnt[tid] = 0;

  const int j0 = tid * 16;
  const uint4* p = (const uint4*)(Hh + (size_t)row * NN + j0);
  const uint4 q0 = p[0], q1 = p[1];
  const unsigned int w[8] = {q0.x, q0.y, q0.z, q0.w, q1.x, q1.y, q1.z, q1.w};
  unsigned int k16[16];
#pragma unroll
  for (int i = 0; i < 16; ++i) {
    const unsigned int u = (i & 1) ? (w[i >> 1] >> 16) : (w[i >> 1] & 0xFFFFu);
    float v = bf2f((u16)u) + ((j0 + i == row) ? 1.f : 0.f);
    const unsigned int b = __float_as_uint(v);
    const unsigned int key = (b & 0x80000000u) ? ~b : (b | 0x80000000u);
    k16[i] = (key >> 16) & 0xFFFFu;
  }
  __syncthreads();                     // covers s_cnt init (keys are private)

  unsigned int pref = 0, kk = 16;
#pragma unroll
  for (int b = 15; b >= 0; --b) {
    const unsigned int hiMask = (0xFFFFu << (b + 1)) & 0xFFFFu;
    const unsigned int want = pref & hiMask;
    unsigned int c = 0;
#pragma unroll
    for (int i = 0; i < 16; ++i)
      c += (((k16[i] & hiMask) == want) & ((k16[i] >> b) & 1u));
#pragma unroll
    for (int off = 32; off > 0; off >>= 1) c += __shfl_down(c, off);
    if ((tid & 63) == 0) atomicAdd(&s_cnt[15 - b], c);
    __syncthreads();                   // one barrier/round (fresh slot each)
    const unsigned int c1 = s_cnt[15 - b];
    if (c1 >= kk) pref |= (1u << b);
    else kk -= c1;
  }
  if (tid == 0) {
    const unsigned int key = pref << 16;
    const unsigned int bits = (key & 0x80000000u) ? (key & 0x7FFFFFFFu) : ~key;
    thr[row] = __uint_as_float(bits);
  }
}

// ---- mask + symmetrize + add I + row-normalize (heat = Y + I) ------------
// Fully vectorized — 16 contiguous elems/thread via uint4/float4, values
// kept in registers (no LDS round-trip).
extern "C" __global__ void __launch_bounds__(256) k_final(
    const u16* __restrict__ Hh,    // Y rows
    const u16* __restrict__ Th,    // Y^T rows
    const float* __restrict__ thr, float* __restrict__ out) {
  __shared__ float wsum[4];
  const int row = blockIdx.x;
  const int tid = threadIdx.x;
  const float ti = thr[row];
  const int j0 = tid * 16;

  const uint4* ph = (const uint4*)(Hh + (size_t)row * NN + j0);
  const uint4* pt = (const uint4*)(Th + (size_t)row * NN + j0);
  const uint4 h0 = ph[0], h1 = ph[1];
  const uint4 t0 = pt[0], t1 = pt[1];
  const unsigned int wh[8] = {h0.x, h0.y, h0.z, h0.w, h1.x, h1.y, h1.z, h1.w};
  const unsigned int wt[8] = {t0.x, t0.y, t0.z, t0.w, t1.x, t1.y, t1.z, t1.w};
  const float4* pr = (const float4*)(thr + j0);
  const float4 r0 = pr[0], r1 = pr[1], r2 = pr[2], r3 = pr[3];
  const float tj[16] = {r0.x, r0.y, r0.z, r0.w, r1.x, r1.y, r1.z, r1.w,
                        r2.x, r2.y, r2.z, r2.w, r3.x, r3.y, r3.z, r3.w};

  float vals[16];
  float s = 0.f;
#pragma unroll
  for (int i = 0; i < 16; ++i) {
    const float ind = (j0 + i == row) ? 1.f : 0.f;
    const unsigned int uh = (i & 1) ? (wh[i >> 1] >> 16) : (wh[i >> 1] & 0xFFFFu);
    const unsigned int ut = (i & 1) ? (wt[i >> 1] >> 16) : (wt[i >> 1] & 0xFFFFu);
    const float hij = bf2f((u16)uh) + ind;
    const float hji = bf2f((u16)ut) + ind;
    float val = (hij >= ti || hji >= tj[i]) ? 0.5f * (hij + hji) : 0.f;
    val += ind;                                   // + eye after masking
    vals[i] = val;
    s += val;
  }
#pragma unroll
  for (int off = 32; off > 0; off >>= 1) s += __shfl_down(s, off);
  if ((tid & 63) == 0) wsum[tid >> 6] = s;
  __syncthreads();
  const float inv = 1.f / (wsum[0] + wsum[1] + wsum[2] + wsum[3]);

  float* op = out + (size_t)row * NN + j0;
#pragma unroll
  for (int q = 0; q < 4; ++q) {
    float4 o;
    o.x = vals[q * 4 + 0] * inv;
    o.y = vals[q * 4 + 1] * inv;
    o.z = vals[q * 4 + 2] * inv;
    o.w = vals[q * 4 + 3] * inv;
    *(float4*)(op + q * 4) = o;
  }
}

extern "C" void kernel_launch(void* const* d_in, const int* in_sizes, int n_in,
                              void* d_out, int out_size, void* d_ws, size_t ws_size,
                              hipStream_t stream) {
  const float* adj = (const float*)d_in[0];
  char* ws = (char*)d_ws;
  const size_t U = (size_t)NN * NN;             // 16 MiB unit (fp8 plane size)
  // ws layout (8U + 16KB): u0-1 Ms16 (later overwritten in-place by Y bf16),
  // u2 MsF, u3 MstF, u4 M2F, u5 GtF, u6-7 Yt16, thr at 8U.
  u16* Ms16 = (u16*)(ws);                       // u0-1 (bf16); Y aliases this
  u8*  MsF  = (u8*)(ws + 2 * U);                // u2
  u8*  MstF = (u8*)(ws + 3 * U);                // u3
  u8*  M2F  = (u8*)(ws + 4 * U);                // u4
  u8*  GtF  = (u8*)(ws + 5 * U);                // u5
  u16* Yt16 = (u16*)(ws + 6 * U);               // u6-7 (Y^T bf16)
  float* thr = (float*)(ws + 8 * U);
  u16* Y16  = Ms16;                             // GEMM2 C16: same-elem RAW-safe
  u16* M2_16 = (u16*)d_out;                     // d_out lower 2U, scratch
  float* out = (float*)d_out;

  const dim3 b(256);
  const u16* n16 = nullptr;
  u8* n8 = nullptr;

  // 1) Ms = -5/2*adj: bf16 -> Ms16, fp8*2^19 -> MsF, (Ms^T)*2^19 -> MstF
  //    (|Ms|max = 2.5/4096 = 6.1e-4 -> *2^19 = 320 < 448 e4m3 max)
  k_split_tr<<<dim3(64, 64), b, 0, stream>>>(adj, Ms16, MsF, MstF,
                                             -2.5f, 0x1p19f);
  // 2) GEMM1: M2 = Ms*Ms; C=M2 (bf16 -> d_out, fp8*2^19 -> M2F);
  //    Ct = G^T = (Ms/6 + M2/24)^T fp8*2^21 -> GtF  (|G|max ~1.2e-4 -> 252)
  k_gemm8<<<dim3(1024), b, 0, stream>>>(MsF, MstF, M2_16, M2F, GtF, (u16*)nullptr,
                                        Ms16, n16,
                                        0x1p-38f, 0.f, 0.f,
                                        1.f / 24.f, 1.f / 6.f, 0.f,
                                        0x1p19f, 0x1p21f);
  // 3) GEMM2: Y = M2*G + Ms + M2/2 -> Y16 (aliases Ms16; same-element
  //    read-before-write in epilogue, safe); Ct16 = Y^T -> Yt16. heat = I + Y.
  k_gemm8<<<dim3(1024), b, 0, stream>>>(M2F, GtF, Y16, n8, n8, Yt16,
                                        Ms16, M2_16,
                                        0x1p-40f, 1.f, 0.5f,
                                        1.f, 1.f, 0.5f,
                                        1.f, 1.f);
  // 4) per-row 16th-largest of heat -> thr (radix-select, register-resident)
  k_topk<<<dim3(NN), b, 0, stream>>>(Y16, thr);
  // 5) mask/sym/normalize -> out (overwrites d_out; M2_16 dead)
  k_final<<<dim3(NN), b, 0, stream>>>(Y16, Yt16, thr, out);
}